// Round 19
// baseline (258.177 us; speedup 1.0000x reference)
//
#include <hip/hip_runtime.h>
#include <hip/hip_bf16.h>
#include <cmath>
#include <cfloat>

constexpr int IN_DIM = 184;
constexpr int KP     = 192;          // padded K for fused layer-0 GEMM
constexpr int HID    = 64;
constexpr int HEADS  = 4;
constexpr int F1     = HEADS * HID;  // 256
constexpr float SLOPE = 0.2f;
constexpr float LN_EPS = 1e-5f;

using short8 = __attribute__((ext_vector_type(8))) short;
using f32x4  = __attribute__((ext_vector_type(4))) float;

__device__ inline float b2f(ushort u) {
    return __uint_as_float(((unsigned)u) << 16);
}
__device__ inline ushort f2b(float f) {
    __hip_bfloat16 b = __float2bfloat16(f);
    return *reinterpret_cast<ushort*>(&b);
}
__device__ inline float lrelu(float e) { return e > 0.f ? e : SLOPE * e; }
__device__ inline float fexp(float x) { return __expf(x); }
__device__ inline float frcp(float x) { return __builtin_amdgcn_rcpf(x); }

// ======== weight prep + csr_count fused ========
__device__ inline size_t frag_idx(int k, int c) {
    int kt = k >> 5, kk = k & 31;
    int q = (kk & 15) >> 2, j = (kk & 3) | ((kk >> 4) << 2);
    int w = c >> 6, ct = (c >> 4) & 3, lr = c & 15;
    int lane = (q << 4) | lr;
    return ((((size_t)kt * 4 + w) * 4 + ct) * 64 + lane) * 8 + j;
}

__device__ inline void edge_sd(const int* __restrict__ ei, int E, int idx, int& s, int& d) {
    if (idx < E) { s = ei[idx]; d = ei[E + idx]; }
    else         { s = idx - E; d = idx - E; }
}

// blocks [0,KP): combined layer-0 weight; [KP,KP+F1): convert W1;
// [KP+F1, ...): csr degree count (deg pre-zeroed).
__global__ __launch_bounds__(256) void weight_prep(const float* __restrict__ Wp,
                                                   const float* __restrict__ W0,
                                                   const float* __restrict__ bp,
                                                   const float* __restrict__ W1,
                                                   ushort* __restrict__ Wf0,
                                                   float* __restrict__ bc,
                                                   ushort* __restrict__ Wf1,
                                                   const int* __restrict__ ei,
                                                   int E, int Etot,
                                                   int* __restrict__ deg) {
    int b = blockIdx.x, c = threadIdx.x;
    if (b < KP) {
        int k = b;
        float s = 0.f;
        if (k < IN_DIM)
            for (int j = 0; j < HID; ++j) s = fmaf(Wp[k * HID + j], W0[j * F1 + c], s);
        Wf0[frag_idx(k, c)] = f2b(s);
        if (k == 0) {
            float bs = 0.f;
            for (int j = 0; j < HID; ++j) bs = fmaf(bp[j], W0[j * F1 + c], bs);
            bc[c] = bs;
        }
    } else if (b < KP + F1) {
        int k = b - KP;
        Wf1[frag_idx(k, c)] = f2b(W1[(size_t)k * F1 + c]);
    } else {
        int idx = (b - KP - F1) * 256 + c;
        if (idx < Etot) {
            int s, d; edge_sd(ei, E, idx, s, d);
            atomicAdd(&deg[d], 1);
        }
    }
}

// ======== staged MFMA GEMM with fused int8-quant + packed-logit epilogue ========
// Outputs: F8 u8 rows; pk[row] = {als bf16 x4, rscale f32, pad} (16B); ald4[row] f32x4.
// L0: role-interleaved with csr_fill (bid%2; 1024 edges per fill block, 4/thread).
template<int KSTEPS, bool L0>
__global__ __launch_bounds__(256) void mfma_gemm2(const void* __restrict__ Xv,
                                                  const ushort* __restrict__ Wfrag,
                                                  const float* __restrict__ bc,
                                                  const float* __restrict__ as_,
                                                  const float* __restrict__ ad_,
                                                  unsigned char* __restrict__ F8,
                                                  uint4* __restrict__ pk,
                                                  float4* __restrict__ ald4,
                                                  int M,
                                                  int gemm_blocks,
                                                  const int* __restrict__ ei,
                                                  int E, int Etot,
                                                  int* __restrict__ wcur,
                                                  int* __restrict__ csr_src) {
    const int tid = threadIdx.x;
    int tile;

    if constexpr (L0) {
        const int bid = blockIdx.x;
        const int gq = bid >> 1, gr = bid & 1;
        const bool is_gemm = (gr == 0) && (gq < gemm_blocks);
        if (!is_gemm) {
            int fid = bid - min((bid + 1) >> 1, gemm_blocks);
            int base = fid * 1024 + tid;
            int sv[4], pv[4];
#pragma unroll
            for (int r = 0; r < 4; ++r) {
                int idx = base + r * 256;
                sv[r] = -1;
                if (idx < Etot) {
                    int s, d; edge_sd(ei, E, idx, s, d);
                    sv[r] = s;
                    pv[r] = atomicAdd(&wcur[d], 1);
                }
            }
#pragma unroll
            for (int r = 0; r < 4; ++r)
                if (sv[r] >= 0) csr_src[pv[r]] = sv[r];
            return;
        }
        tile = gq;
    } else {
        tile = blockIdx.x;
    }

    const int w = tid >> 6, l = tid & 63;
    const int lr = l & 15, q = l >> 4;
    const int row0 = tile * 64;

    __shared__ ushort a_lds[2][64][40];
    __shared__ float rmax_lds[64][4];
    __shared__ float als_lds[64][4];
    __shared__ float ald_lds[64][4];

    const int srow = tid >> 2, seg = tid & 3;
    int grow = row0 + srow; if (grow >= M) grow = M - 1;

    auto stage = [&](int buf, int kt) {
        if constexpr (!L0) {
            const ushort* p = (const ushort*)Xv + (size_t)grow * 256 + kt * 32 + seg * 8;
            *(uint4*)&a_lds[buf][srow][seg * 8] = *(const uint4*)p;
        } else {
            int kb = kt * 32 + seg * 8;
            uint4 o = {0u, 0u, 0u, 0u};
            if (kb < IN_DIM) {
                const float* p = (const float*)Xv + (size_t)grow * IN_DIM + kb;
                float4 lo = *(const float4*)p;
                float4 hi = *(const float4*)(p + 4);
                o.x = (uint)f2b(lo.x) | ((uint)f2b(lo.y) << 16);
                o.y = (uint)f2b(lo.z) | ((uint)f2b(lo.w) << 16);
                o.z = (uint)f2b(hi.x) | ((uint)f2b(hi.y) << 16);
                o.w = (uint)f2b(hi.z) | ((uint)f2b(hi.w) << 16);
            }
            *(uint4*)&a_lds[buf][srow][seg * 8] = o;
        }
    };

    f32x4 acc[4][4] = {};

    stage(0, 0);
    short8 bcur[4];
#pragma unroll
    for (int ct = 0; ct < 4; ++ct) {
        const ushort* bp = Wfrag + ((((size_t)0 * 4 + w) * 4 + ct) * 64 + l) * 8;
        short8 b; *(uint4*)&b = *(const uint4*)bp; bcur[ct] = b;
    }
    __syncthreads();

    int buf = 0;
#pragma unroll
    for (int kt = 0; kt < KSTEPS; ++kt) {
        short8 bnext[4];
        if (kt + 1 < KSTEPS) {
#pragma unroll
            for (int ct = 0; ct < 4; ++ct) {
                const ushort* bp = Wfrag + ((((size_t)(kt + 1) * 4 + w) * 4 + ct) * 64 + l) * 8;
                short8 b; *(uint4*)&b = *(const uint4*)bp; bnext[ct] = b;
            }
            stage(buf ^ 1, kt + 1);
        }
        short8 afr[4];
#pragma unroll
        for (int rt = 0; rt < 4; ++rt) {
            short8 a;
            *(uint2*)&a       = *(const uint2*)&a_lds[buf][rt * 16 + lr][4 * q];
            *((uint2*)&a + 1) = *(const uint2*)&a_lds[buf][rt * 16 + lr][4 * q + 16];
            afr[rt] = a;
        }
#pragma unroll
        for (int rt = 0; rt < 4; ++rt)
#pragma unroll
            for (int ct = 0; ct < 4; ++ct)
                acc[rt][ct] = __builtin_amdgcn_mfma_f32_16x16x32_bf16(afr[rt], bcur[ct], acc[rt][ct], 0, 0, 0);
        __syncthreads();
        if (kt + 1 < KSTEPS) {
#pragma unroll
            for (int ct = 0; ct < 4; ++ct) bcur[ct] = bnext[ct];
        }
        buf ^= 1;
    }

    if constexpr (L0) {
        float bcv[4];
#pragma unroll
        for (int ct = 0; ct < 4; ++ct) bcv[ct] = bc[w * 64 + ct * 16 + lr];
#pragma unroll
        for (int rt = 0; rt < 4; ++rt)
#pragma unroll
            for (int ct = 0; ct < 4; ++ct)
#pragma unroll
                for (int r = 0; r < 4; ++r) acc[rt][ct][r] += bcv[ct];
    }

    // ---- per-row absmax (this wave's 64 cols) -> LDS ----
#pragma unroll
    for (int rt = 0; rt < 4; ++rt) {
#pragma unroll
        for (int r = 0; r < 4; ++r) {
            float m = fmaxf(fmaxf(fabsf(acc[rt][0][r]), fabsf(acc[rt][1][r])),
                            fmaxf(fabsf(acc[rt][2][r]), fabsf(acc[rt][3][r])));
            m = fmaxf(m, __shfl_xor(m, 1));
            m = fmaxf(m, __shfl_xor(m, 2));
            m = fmaxf(m, __shfl_xor(m, 4));
            m = fmaxf(m, __shfl_xor(m, 8));
            if (lr == 0) rmax_lds[rt * 16 + q * 4 + r][w] = m;
        }
    }
    __syncthreads();

    // ---- quantize + store F8 ----
#pragma unroll
    for (int rt = 0; rt < 4; ++rt) {
#pragma unroll
        for (int r = 0; r < 4; ++r) {
            int lrow = rt * 16 + q * 4 + r;
            float m = fmaxf(fmaxf(rmax_lds[lrow][0], rmax_lds[lrow][1]),
                            fmaxf(rmax_lds[lrow][2], rmax_lds[lrow][3]));
            float inv = (m > 0.f) ? 127.f / m : 0.f;
            int row = row0 + lrow;
            if (row < M) {
#pragma unroll
                for (int ct = 0; ct < 4; ++ct) {
                    int qv = (int)rintf(acc[rt][ct][r] * inv) + 128;
                    qv = min(max(qv, 0), 255);
                    F8[(size_t)row * 256 + w * 64 + ct * 16 + lr] = (unsigned char)qv;
                }
            }
        }
    }

    // ---- attention logits -> LDS ----
    float asv[4], adv[4];
#pragma unroll
    for (int ct = 0; ct < 4; ++ct) {
        asv[ct] = as_[w * 64 + ct * 16 + lr];
        adv[ct] = ad_[w * 64 + ct * 16 + lr];
    }
#pragma unroll
    for (int rt = 0; rt < 4; ++rt) {
#pragma unroll
        for (int r = 0; r < 4; ++r) {
            float ls = 0.f, ld_ = 0.f;
#pragma unroll
            for (int ct = 0; ct < 4; ++ct) {
                ls  = fmaf(acc[rt][ct][r], asv[ct], ls);
                ld_ = fmaf(acc[rt][ct][r], adv[ct], ld_);
            }
            for (int off = 8; off; off >>= 1) {
                ls  += __shfl_xor(ls, off);
                ld_ += __shfl_xor(ld_, off);
            }
            if (lr == 0) {
                int lrow = rt * 16 + q * 4 + r;
                als_lds[lrow][w] = ls;
                ald_lds[lrow][w] = ld_;
            }
        }
    }
    __syncthreads();

    // ---- pack: pk[row] = {als bf16x4, rscale, 0}; ald4[row] f32x4 ----
    if (tid < 64) {
        int row = row0 + tid;
        if (row < M) {
            float m = fmaxf(fmaxf(rmax_lds[tid][0], rmax_lds[tid][1]),
                            fmaxf(rmax_lds[tid][2], rmax_lds[tid][3]));
            uint a01 = (uint)f2b(als_lds[tid][0]) | ((uint)f2b(als_lds[tid][1]) << 16);
            uint a23 = (uint)f2b(als_lds[tid][2]) | ((uint)f2b(als_lds[tid][3]) << 16);
            pk[row] = uint4{ a01, a23, __float_as_uint(m * (1.f / 127.f)), 0u };
            ald4[row] = float4{ ald_lds[tid][0], ald_lds[tid][1],
                                ald_lds[tid][2], ald_lds[tid][3] };
        }
    }
}

// ---------------- CSR scans (scan2 folded into scan3) ----------------
__global__ __launch_bounds__(256) void scan1(const int* __restrict__ deg, int* __restrict__ out,
                                             int* __restrict__ csum, int N) {
    __shared__ int s[256];
    int t = threadIdx.x;
    int idx0 = blockIdx.x * 1024 + t * 4;
    int v[4];
#pragma unroll
    for (int i = 0; i < 4; ++i) { int id = idx0 + i; v[i] = (id < N) ? deg[id] : 0; }
    int sum = v[0] + v[1] + v[2] + v[3];
    s[t] = sum; __syncthreads();
    for (int off = 1; off < 256; off <<= 1) {
        int x = (t >= off) ? s[t - off] : 0;
        __syncthreads();
        s[t] += x;
        __syncthreads();
    }
    int run = (t == 0) ? 0 : s[t - 1];
#pragma unroll
    for (int i = 0; i < 4; ++i) {
        run += v[i];
        int id = idx0 + i;
        if (id < N) out[id] = run;
    }
    if (t == 255) csum[blockIdx.x] = s[255];
}

__global__ __launch_bounds__(256) void scan3(const int* __restrict__ deg, int* __restrict__ rend,
                                             const int* __restrict__ csum, int* __restrict__ wcur, int N) {
    int id = blockIdx.x * 256 + threadIdx.x;
    if (id >= N) return;
    int chunk = id >> 10;
    int off = 0;
    for (int i = 0; i < chunk; ++i) off += csum[i];
    int e = rend[id] + off;
    rend[id] = e;
    wcur[id] = e - deg[id];
}

// ======== fused softmax (max-free, packed logits) + int8 gather + LN(+res)+ELU ========
template<bool RES, bool FEAT2>
__global__ __launch_bounds__(128) void aggregate_fused(const int* __restrict__ csr_src,
                                                       const int* __restrict__ rend,
                                                       const int* __restrict__ deg_,
                                                       const unsigned char* __restrict__ feat,
                                                       const uint4* __restrict__ pk,
                                                       const float4* __restrict__ ald4,
                                                       const float* __restrict__ bias,
                                                       const float* __restrict__ g,
                                                       const float* __restrict__ bln,
                                                       const ushort* __restrict__ res,
                                                       ushort* __restrict__ out_bf,
                                                       const float* __restrict__ W2,
                                                       const float* __restrict__ as2,
                                                       const float* __restrict__ ad2,
                                                       float4* __restrict__ nf2,
                                                       int N) {
    __shared__ __align__(16) float alds[2][64][4];
    __shared__ int srcs[2][64];
    const int w = threadIdx.x >> 6, l = threadIdx.x & 63;
    const int n = blockIdx.x * 2 + w;
    if (n >= N) return;
    const int dg = deg_[n], end = rend[n], start = end - dg;
    const int hf = l >> 5;
    const int lh = l & 31;
    const int hh = lh >> 3;
    const float4 ad4 = ald4[n];

    float acc[8] = {0.f, 0.f, 0.f, 0.f, 0.f, 0.f, 0.f, 0.f};
    float accC = 0.f;

    auto fma8 = [&](uint2 u, float b) {
        acc[0] = fmaf((float)( u.x        & 0xffu), b, acc[0]);
        acc[1] = fmaf((float)((u.x >>  8) & 0xffu), b, acc[1]);
        acc[2] = fmaf((float)((u.x >> 16) & 0xffu), b, acc[2]);
        acc[3] = fmaf((float)( u.x >> 24         ), b, acc[3]);
        acc[4] = fmaf((float)( u.y        & 0xffu), b, acc[4]);
        acc[5] = fmaf((float)((u.y >>  8) & 0xffu), b, acc[5]);
        acc[6] = fmaf((float)((u.y >> 16) & 0xffu), b, acc[6]);
        acc[7] = fmaf((float)( u.y >> 24         ), b, acc[7]);
        accC += b;
    };

    auto LD = [&](int j) -> uint2 {
        int s = srcs[w][j];
        return *(const uint2*)&feat[(size_t)s * 256 + lh * 8];
    };

    auto gather_chunk = [&](int cnt) {
        int j = hf;
        for (; j + 2 < cnt; j += 4) {
            uint2 u0 = LD(j);
            uint2 u1 = LD(j + 2);
            fma8(u0, alds[w][j][hh]);
            fma8(u1, alds[w][j + 2][hh]);
        }
        for (; j < cnt; j += 2) {
            uint2 u0 = LD(j);
            fma8(u0, alds[w][j][hh]);
        }
    };

    auto exp4_of = [&](uint4 p) -> float4 {
        float4 e;
        e.x = fexp(lrelu(b2f((ushort)(p.x & 0xffff)) + ad4.x));
        e.y = fexp(lrelu(b2f((ushort)(p.x >> 16))    + ad4.y));
        e.z = fexp(lrelu(b2f((ushort)(p.y & 0xffff)) + ad4.z));
        e.w = fexp(lrelu(b2f((ushort)(p.y >> 16))    + ad4.w));
        return e;
    };

    if (dg <= 64) {
        int s = 0;
        float sc = 0.f;
        float4 ex = { 0.f, 0.f, 0.f, 0.f };
        if (l < dg) {
            s = csr_src[start + l];
            uint4 p = pk[s];
            sc = __uint_as_float(p.z);
            ex = exp4_of(p);
        }
        float4 sum = ex;
        for (int off = 32; off; off >>= 1) {
            sum.x += __shfl_xor(sum.x, off);
            sum.y += __shfl_xor(sum.y, off);
            sum.z += __shfl_xor(sum.z, off);
            sum.w += __shfl_xor(sum.w, off);
        }
        float4 al = { ex.x * frcp(sum.x + 1e-16f) * sc, ex.y * frcp(sum.y + 1e-16f) * sc,
                      ex.z * frcp(sum.z + 1e-16f) * sc, ex.w * frcp(sum.w + 1e-16f) * sc };
        *(float4*)&alds[w][l][0] = al;
        srcs[w][l] = s;
        __builtin_amdgcn_s_waitcnt(0);
        gather_chunk(dg);
    } else {
        float4 sum = { 0.f, 0.f, 0.f, 0.f };
        for (int i = l; i < dg; i += 64) {
            int s = csr_src[start + i];
            float4 e = exp4_of(pk[s]);
            sum.x += e.x; sum.y += e.y; sum.z += e.z; sum.w += e.w;
        }
        for (int off = 32; off; off >>= 1) {
            sum.x += __shfl_xor(sum.x, off);
            sum.y += __shfl_xor(sum.y, off);
            sum.z += __shfl_xor(sum.z, off);
            sum.w += __shfl_xor(sum.w, off);
        }
        float4 inv = { frcp(sum.x + 1e-16f), frcp(sum.y + 1e-16f),
                       frcp(sum.z + 1e-16f), frcp(sum.w + 1e-16f) };
        for (int c0 = start; c0 < end; c0 += 64) {
            int cnt = min(64, end - c0);
            if (l < cnt) {
                int s = csr_src[c0 + l];
                uint4 p = pk[s];
                float sc = __uint_as_float(p.z);
                float4 e = exp4_of(p);
                float4 al = { e.x * inv.x * sc, e.y * inv.y * sc,
                              e.z * inv.z * sc, e.w * inv.w * sc };
                *(float4*)&alds[w][l][0] = al;
                srcs[w][l] = s;
            }
            __builtin_amdgcn_s_waitcnt(0);
            gather_chunk(cnt);
        }
    }

#pragma unroll
    for (int r = 0; r < 8; ++r) acc[r] += __shfl_xor(acc[r], 32);
    accC += __shfl_xor(accC, 32);

    float4 bv0 = ((const float4*)bias)[lh * 2];
    float4 bv1 = ((const float4*)bias)[lh * 2 + 1];
    float c128 = 128.f * accC;
    float v[8] = { acc[0] - c128 + bv0.x, acc[1] - c128 + bv0.y,
                   acc[2] - c128 + bv0.z, acc[3] - c128 + bv0.w,
                   acc[4] - c128 + bv1.x, acc[5] - c128 + bv1.y,
                   acc[6] - c128 + bv1.z, acc[7] - c128 + bv1.w };
    float sm = v[0] + v[1] + v[2] + v[3] + v[4] + v[5] + v[6] + v[7];
    for (int off = 32; off; off >>= 1) sm += __shfl_xor(sm, off);
    float mu = sm * (1.f / (2 * F1));
    float dv = 0.f;
#pragma unroll
    for (int r = 0; r < 8; ++r) { float d = v[r] - mu; dv += d * d; }
    for (int off = 32; off; off >>= 1) dv += __shfl_xor(dv, off);
    float rstd = rsqrtf(dv * (1.f / (2 * F1)) + LN_EPS);
    float4 gv0 = ((const float4*)g)[lh * 2],   gv1 = ((const float4*)g)[lh * 2 + 1];
    float4 lb0 = ((const float4*)bln)[lh * 2], lb1 = ((const float4*)bln)[lh * 2 + 1];
    float y[8];
    y[0] = (v[0] - mu) * rstd * gv0.x + lb0.x;
    y[1] = (v[1] - mu) * rstd * gv0.y + lb0.y;
    y[2] = (v[2] - mu) * rstd * gv0.z + lb0.z;
    y[3] = (v[3] - mu) * rstd * gv0.w + lb0.w;
    y[4] = (v[4] - mu) * rstd * gv1.x + lb1.x;
    y[5] = (v[5] - mu) * rstd * gv1.y + lb1.y;
    y[6] = (v[6] - mu) * rstd * gv1.z + lb1.z;
    y[7] = (v[7] - mu) * rstd * gv1.w + lb1.w;
    if (RES) {
        uint4 rr = ((const uint4*)res)[(size_t)n * 32 + lh];
        y[0] += __uint_as_float(rr.x << 16);
        y[1] += __uint_as_float(rr.x & 0xffff0000u);
        y[2] += __uint_as_float(rr.y << 16);
        y[3] += __uint_as_float(rr.y & 0xffff0000u);
        y[4] += __uint_as_float(rr.z << 16);
        y[5] += __uint_as_float(rr.z & 0xffff0000u);
        y[6] += __uint_as_float(rr.w << 16);
        y[7] += __uint_as_float(rr.w & 0xffff0000u);
    }
#pragma unroll
    for (int r = 0; r < 8; ++r) y[r] = y[r] > 0.f ? y[r] : fexp(y[r]) - 1.f;

    if (!FEAT2) {
        if (l < 32) {
            uint4 o;
            o.x = (uint)f2b(y[0]) | ((uint)f2b(y[1]) << 16);
            o.y = (uint)f2b(y[2]) | ((uint)f2b(y[3]) << 16);
            o.z = (uint)f2b(y[4]) | ((uint)f2b(y[5]) << 16);
            o.w = (uint)f2b(y[6]) | ((uint)f2b(y[7]) << 16);
            ((uint4*)out_bf)[(size_t)n * 32 + lh] = o;
        }
    } else {
        const float4* W24 = (const float4*)W2;
        float c0 = 0.f, c1 = 0.f;
#pragma unroll
        for (int j = 0; j < 4; ++j) {
            float4 wv = W24[lh * 4 + j];
            c0 += y[2 * j] * wv.x + y[2 * j + 1] * wv.z;
            c1 += y[2 * j] * wv.y + y[2 * j + 1] * wv.w;
        }
        for (int off = 32; off; off >>= 1) {
            c0 += __shfl_xor(c0, off);
            c1 += __shfl_xor(c1, off);
        }
        c0 *= 0.5f; c1 *= 0.5f;
        if (l == 0) {
            float4 o = { c0, c1,
                         c0 * as2[0] + c1 * as2[1],
                         c0 * ad2[0] + c1 * ad2[1] };
            nf2[n] = o;
        }
    }
}

// ---- layer 2 fully fused (max-free softmax) ----
__global__ __launch_bounds__(128) void layer2_fused(const int* __restrict__ csr_src,
                                                    const int* __restrict__ rend,
                                                    const int* __restrict__ deg_,
                                                    const float4* __restrict__ nf2,
                                                    const float* __restrict__ b2,
                                                    float* __restrict__ out, int N) {
    const int w = threadIdx.x >> 6, l = threadIdx.x & 63;
    const int n = blockIdx.x * 2 + w;
    if (n >= N) return;
    const int dg = deg_[n], end = rend[n], start = end - dg;
    const float ad = nf2[n].w;

    float a0 = 0.f, a1 = 0.f;
    if (dg <= 64) {
        float ex = 0.f;
        float f0 = 0.f, f1 = 0.f;
        if (l < dg) {
            int s = csr_src[start + l];
            float4 v = nf2[s];
            ex = fexp(lrelu(v.z + ad));
            f0 = v.x; f1 = v.y;
        }
        float sum = ex;
        for (int off = 32; off; off >>= 1) sum += __shfl_xor(sum, off);
        float al = ex * frcp(sum + 1e-16f);
        a0 = f0 * al; a1 = f1 * al;
    } else {
        float sum = 0.f;
        for (int i = l; i < dg; i += 64) {
            int s = csr_src[start + i];
            sum += fexp(lrelu(nf2[s].z + ad));
        }
        for (int off = 32; off; off >>= 1) sum += __shfl_xor(sum, off);
        float inv = frcp(sum + 1e-16f);
        for (int i = l; i < dg; i += 64) {
            int s = csr_src[start + i];
            float4 v = nf2[s];
            float al = fexp(lrelu(v.z + ad)) * inv;
            a0 = fmaf(v.x, al, a0);
            a1 = fmaf(v.y, al, a1);
        }
    }
    for (int off = 32; off; off >>= 1) {
        a0 += __shfl_xor(a0, off);
        a1 += __shfl_xor(a1, off);
    }
    if (l == 0) {
        out[(size_t)n * 2 + 0] = a0 + b2[0];
        out[(size_t)n * 2 + 1] = a1 + b2[1];
    }
}

extern "C" void kernel_launch(void* const* d_in, const int* in_sizes, int n_in,
                              void* d_out, int out_size, void* d_ws, size_t ws_size,
                              hipStream_t stream) {
    const float* x    = (const float*)d_in[0];
    const int*   ei   = (const int*)d_in[1];
    const float* Wp   = (const float*)d_in[2];
    const float* bp   = (const float*)d_in[3];
    const float* W0   = (const float*)d_in[4];
    const float* as0  = (const float*)d_in[5];
    const float* ad0  = (const float*)d_in[6];
    const float* b0   = (const float*)d_in[7];
    const float* W1   = (const float*)d_in[8];
    const float* as1  = (const float*)d_in[9];
    const float* ad1  = (const float*)d_in[10];
    const float* b1   = (const float*)d_in[11];
    const float* W2   = (const float*)d_in[12];
    const float* as2  = (const float*)d_in[13];
    const float* ad2  = (const float*)d_in[14];
    const float* b2   = (const float*)d_in[15];
    const float* ln_g = (const float*)d_in[16];
    const float* ln_b = (const float*)d_in[17];
    float* out = (float*)d_out;

    const int N    = in_sizes[0] / IN_DIM;   // 50000
    const int E    = in_sizes[1] / 2;        // 800000
    const int Etot = E + N;

    char* wptr = (char*)d_ws;
    auto alloc = [&](size_t bytes) -> void* {
        void* p = wptr;
        wptr += (bytes + 255) & ~(size_t)255;
        return p;
    };
    unsigned char* F8 = (unsigned char*)alloc((size_t)N * F1);
    uint4*  pk     = (uint4*)alloc(sizeof(uint4) * (size_t)N);
    float4* ald4   = (float4*)alloc(sizeof(float4) * (size_t)N);
    ushort* Ab     = (ushort*)alloc(sizeof(ushort) * (size_t)N * F1);
    float4* nf2    = (float4*)alloc(sizeof(float4) * (size_t)N);
    ushort* Wf0    = (ushort*)alloc(sizeof(ushort) * (size_t)F1 * KP);
    float*  bc     = (float*)alloc(sizeof(float) * F1);
    ushort* Wf1    = (ushort*)alloc(sizeof(ushort) * (size_t)F1 * F1);
    int*    deg    = (int*)alloc(sizeof(int) * (size_t)N);
    int*    rend   = (int*)alloc(sizeof(int) * (size_t)N);
    int*    wcur   = (int*)alloc(sizeof(int) * (size_t)N);
    int*    csum   = (int*)alloc(sizeof(int) * 256);
    int*    csrs   = (int*)alloc(sizeof(int) * (size_t)Etot);

    const int eb   = (Etot + 255) / 256;
    const int eb4  = (Etot + 1023) / 1024;   // fill blocks (4 edges/thread)
    const int nb   = (N + 255) / 256;
    const int nb2  = (N + 1) / 2;
    const int nchunks = (N + 1023) / 1024;
    const int mb64 = (N + 63) / 64;

    // -------- weight prep + csr degree count (one dispatch) --------
    hipMemsetAsync(deg, 0, sizeof(int) * (size_t)N, stream);
    weight_prep<<<KP + F1 + eb, 256, 0, stream>>>(Wp, W0, bp, W1, Wf0, bc, Wf1,
                                                  ei, E, Etot, deg);

    // -------- CSR scans --------
    scan1<<<nchunks, 256, 0, stream>>>(deg, rend, csum, N);
    scan3<<<nb, 256, 0, stream>>>(deg, rend, csum, wcur, N);

    // ====== layer 0 GEMM + csr_fill, role-interleaved (bid%2) ======
    mfma_gemm2<KP / 32, true><<<mb64 + eb4, 256, 0, stream>>>(
        x, Wf0, bc, as0, ad0, F8, pk, ald4, N,
        mb64, ei, E, Etot, wcur, csrs);
    aggregate_fused<false, false><<<nb2, 128, 0, stream>>>(csrs, rend, deg, F8, pk, ald4,
        b0, ln_g, ln_b, nullptr, Ab, nullptr, nullptr, nullptr, nullptr, N);

    // ================= layer 1 =================
    mfma_gemm2<F1 / 32, false><<<mb64, 256, 0, stream>>>(
        Ab, Wf1, nullptr, as1, ad1, F8, pk, ald4, N,
        mb64, nullptr, 0, 0, nullptr, nullptr);
    aggregate_fused<true, true><<<nb2, 128, 0, stream>>>(csrs, rend, deg, F8, pk, ald4,
        b1, ln_g, ln_b, Ab, nullptr, W2, as2, ad2, nf2, N);

    // ================= layer 2 =================
    layer2_fused<<<nb2, 128, 0, stream>>>(csrs, rend, deg, nf2, b2, out, N);
}

// Round 20
// 248.860 us; speedup vs baseline: 1.0374x; 1.0374x over previous
//
#include <hip/hip_runtime.h>
#include <hip/hip_bf16.h>
#include <cmath>
#include <cfloat>

constexpr int IN_DIM = 184;
constexpr int KP     = 192;          // padded K for fused layer-0 GEMM
constexpr int HID    = 64;
constexpr int HEADS  = 4;
constexpr int F1     = HEADS * HID;  // 256
constexpr float SLOPE = 0.2f;
constexpr float LN_EPS = 1e-5f;

using short8 = __attribute__((ext_vector_type(8))) short;
using f32x4  = __attribute__((ext_vector_type(4))) float;

__device__ inline float b2f(ushort u) {
    return __uint_as_float(((unsigned)u) << 16);
}
__device__ inline ushort f2b(float f) {
    __hip_bfloat16 b = __float2bfloat16(f);
    return *reinterpret_cast<ushort*>(&b);
}
__device__ inline float lrelu(float e) { return e > 0.f ? e : SLOPE * e; }
__device__ inline float fexp(float x) { return __expf(x); }
__device__ inline float frcp(float x) { return __builtin_amdgcn_rcpf(x); }

// ======== weight prep + csr_count fused ========
__device__ inline size_t frag_idx(int k, int c) {
    int kt = k >> 5, kk = k & 31;
    int q = (kk & 15) >> 2, j = (kk & 3) | ((kk >> 4) << 2);
    int w = c >> 6, ct = (c >> 4) & 3, lr = c & 15;
    int lane = (q << 4) | lr;
    return ((((size_t)kt * 4 + w) * 4 + ct) * 64 + lane) * 8 + j;
}

__device__ inline void edge_sd(const int* __restrict__ ei, int E, int idx, int& s, int& d) {
    if (idx < E) { s = ei[idx]; d = ei[E + idx]; }
    else         { s = idx - E; d = idx - E; }
}

// blocks [0,KP): combined layer-0 weight; [KP,KP+F1): convert W1;
// [KP+F1, ...): csr degree count (deg pre-zeroed).
__global__ __launch_bounds__(256) void weight_prep(const float* __restrict__ Wp,
                                                   const float* __restrict__ W0,
                                                   const float* __restrict__ bp,
                                                   const float* __restrict__ W1,
                                                   ushort* __restrict__ Wf0,
                                                   float* __restrict__ bc,
                                                   ushort* __restrict__ Wf1,
                                                   const int* __restrict__ ei,
                                                   int E, int Etot,
                                                   int* __restrict__ deg) {
    int b = blockIdx.x, c = threadIdx.x;
    if (b < KP) {
        int k = b;
        float s = 0.f;
        if (k < IN_DIM)
            for (int j = 0; j < HID; ++j) s = fmaf(Wp[k * HID + j], W0[j * F1 + c], s);
        Wf0[frag_idx(k, c)] = f2b(s);
        if (k == 0) {
            float bs = 0.f;
            for (int j = 0; j < HID; ++j) bs = fmaf(bp[j], W0[j * F1 + c], bs);
            bc[c] = bs;
        }
    } else if (b < KP + F1) {
        int k = b - KP;
        Wf1[frag_idx(k, c)] = f2b(W1[(size_t)k * F1 + c]);
    } else {
        int idx = (b - KP - F1) * 256 + c;
        if (idx < Etot) {
            int s, d; edge_sd(ei, E, idx, s, d);
            atomicAdd(&deg[d], 1);
        }
    }
}

// ======== staged MFMA GEMM with fused int8-quant + packed-logit epilogue ========
// Outputs: F8 u8 rows; pk[row] = {als bf16 x4, rscale f32, pad}; ald4[row] f32x4.
// L0: role-interleaved with csr_fill (every 3rd block = GEMM; fill 512 edges/block).
// Epilogue LDS aliases the (dead) A-staging buffer to keep LDS at 10240 B.
template<int KSTEPS, bool L0>
__global__ __launch_bounds__(256) void mfma_gemm2(const void* __restrict__ Xv,
                                                  const ushort* __restrict__ Wfrag,
                                                  const float* __restrict__ bc,
                                                  const float* __restrict__ as_,
                                                  const float* __restrict__ ad_,
                                                  unsigned char* __restrict__ F8,
                                                  uint4* __restrict__ pk,
                                                  float4* __restrict__ ald4,
                                                  int M,
                                                  int gemm_blocks,
                                                  const int* __restrict__ ei,
                                                  int E, int Etot,
                                                  int* __restrict__ wcur,
                                                  int* __restrict__ csr_src) {
    const int tid = threadIdx.x;
    int tile;

    if constexpr (L0) {
        const int bid = blockIdx.x;
        const bool is_gemm = (bid % 3 == 0) && (bid / 3 < gemm_blocks);
        if (!is_gemm) {
            int ng = min((bid + 2) / 3, gemm_blocks);   // gemm blocks with index < bid
            int fid = bid - ng;
            int base = fid * 512 + tid;
#pragma unroll
            for (int r = 0; r < 2; ++r) {
                int idx = base + r * 256;
                if (idx < Etot) {
                    int s, d; edge_sd(ei, E, idx, s, d);
                    int pos = atomicAdd(&wcur[d], 1);
                    csr_src[pos] = s;
                }
            }
            return;
        }
        tile = bid / 3;
    } else {
        tile = blockIdx.x;
    }

    const int w = tid >> 6, l = tid & 63;
    const int lr = l & 15, q = l >> 4;
    const int row0 = tile * 64;

    __shared__ __align__(16) ushort a_lds[2][64][40];   // 10240 B; reused by epilogue
    float* rmax_lds = (float*)&a_lds[0][0][0];          // [64][4]
    float* als_lds  = rmax_lds + 256;                   // [64][4]
    float* ald_lds  = als_lds + 256;                    // [64][4]

    const int srow = tid >> 2, seg = tid & 3;
    int grow = row0 + srow; if (grow >= M) grow = M - 1;

    auto stage = [&](int buf, int kt) {
        if constexpr (!L0) {
            const ushort* p = (const ushort*)Xv + (size_t)grow * 256 + kt * 32 + seg * 8;
            *(uint4*)&a_lds[buf][srow][seg * 8] = *(const uint4*)p;
        } else {
            int kb = kt * 32 + seg * 8;
            uint4 o = {0u, 0u, 0u, 0u};
            if (kb < IN_DIM) {
                const float* p = (const float*)Xv + (size_t)grow * IN_DIM + kb;
                float4 lo = *(const float4*)p;
                float4 hi = *(const float4*)(p + 4);
                o.x = (uint)f2b(lo.x) | ((uint)f2b(lo.y) << 16);
                o.y = (uint)f2b(lo.z) | ((uint)f2b(lo.w) << 16);
                o.z = (uint)f2b(hi.x) | ((uint)f2b(hi.y) << 16);
                o.w = (uint)f2b(hi.z) | ((uint)f2b(hi.w) << 16);
            }
            *(uint4*)&a_lds[buf][srow][seg * 8] = o;
        }
    };

    f32x4 acc[4][4] = {};

    stage(0, 0);
    short8 bcur[4];
#pragma unroll
    for (int ct = 0; ct < 4; ++ct) {
        const ushort* bp = Wfrag + ((((size_t)0 * 4 + w) * 4 + ct) * 64 + l) * 8;
        short8 b; *(uint4*)&b = *(const uint4*)bp; bcur[ct] = b;
    }
    __syncthreads();

    int buf = 0;
#pragma unroll
    for (int kt = 0; kt < KSTEPS; ++kt) {
        short8 bnext[4];
        if (kt + 1 < KSTEPS) {
#pragma unroll
            for (int ct = 0; ct < 4; ++ct) {
                const ushort* bp = Wfrag + ((((size_t)(kt + 1) * 4 + w) * 4 + ct) * 64 + l) * 8;
                short8 b; *(uint4*)&b = *(const uint4*)bp; bnext[ct] = b;
            }
            stage(buf ^ 1, kt + 1);
        }
        short8 afr[4];
#pragma unroll
        for (int rt = 0; rt < 4; ++rt) {
            short8 a;
            *(uint2*)&a       = *(const uint2*)&a_lds[buf][rt * 16 + lr][4 * q];
            *((uint2*)&a + 1) = *(const uint2*)&a_lds[buf][rt * 16 + lr][4 * q + 16];
            afr[rt] = a;
        }
#pragma unroll
        for (int rt = 0; rt < 4; ++rt)
#pragma unroll
            for (int ct = 0; ct < 4; ++ct)
                acc[rt][ct] = __builtin_amdgcn_mfma_f32_16x16x32_bf16(afr[rt], bcur[ct], acc[rt][ct], 0, 0, 0);
        __syncthreads();
        if (kt + 1 < KSTEPS) {
#pragma unroll
            for (int ct = 0; ct < 4; ++ct) bcur[ct] = bnext[ct];
        }
        buf ^= 1;
    }
    // a_lds is dead from here on; epilogue arrays alias it (post-loop barrier done).

    if constexpr (L0) {
        float bcv[4];
#pragma unroll
        for (int ct = 0; ct < 4; ++ct) bcv[ct] = bc[w * 64 + ct * 16 + lr];
#pragma unroll
        for (int rt = 0; rt < 4; ++rt)
#pragma unroll
            for (int ct = 0; ct < 4; ++ct)
#pragma unroll
                for (int r = 0; r < 4; ++r) acc[rt][ct][r] += bcv[ct];
    }

    // ---- per-row absmax (this wave's 64 cols) -> LDS ----
#pragma unroll
    for (int rt = 0; rt < 4; ++rt) {
#pragma unroll
        for (int r = 0; r < 4; ++r) {
            float m = fmaxf(fmaxf(fabsf(acc[rt][0][r]), fabsf(acc[rt][1][r])),
                            fmaxf(fabsf(acc[rt][2][r]), fabsf(acc[rt][3][r])));
            m = fmaxf(m, __shfl_xor(m, 1));
            m = fmaxf(m, __shfl_xor(m, 2));
            m = fmaxf(m, __shfl_xor(m, 4));
            m = fmaxf(m, __shfl_xor(m, 8));
            if (lr == 0) rmax_lds[(rt * 16 + q * 4 + r) * 4 + w] = m;
        }
    }
    __syncthreads();

    // ---- quantize + store F8 ----
#pragma unroll
    for (int rt = 0; rt < 4; ++rt) {
#pragma unroll
        for (int r = 0; r < 4; ++r) {
            int lrow = rt * 16 + q * 4 + r;
            float m = fmaxf(fmaxf(rmax_lds[lrow * 4 + 0], rmax_lds[lrow * 4 + 1]),
                            fmaxf(rmax_lds[lrow * 4 + 2], rmax_lds[lrow * 4 + 3]));
            float inv = (m > 0.f) ? 127.f / m : 0.f;
            int row = row0 + lrow;
            if (row < M) {
#pragma unroll
                for (int ct = 0; ct < 4; ++ct) {
                    int qv = (int)rintf(acc[rt][ct][r] * inv) + 128;
                    qv = min(max(qv, 0), 255);
                    F8[(size_t)row * 256 + w * 64 + ct * 16 + lr] = (unsigned char)qv;
                }
            }
        }
    }

    // ---- attention logits -> LDS ----
    float asv[4], adv[4];
#pragma unroll
    for (int ct = 0; ct < 4; ++ct) {
        asv[ct] = as_[w * 64 + ct * 16 + lr];
        adv[ct] = ad_[w * 64 + ct * 16 + lr];
    }
#pragma unroll
    for (int rt = 0; rt < 4; ++rt) {
#pragma unroll
        for (int r = 0; r < 4; ++r) {
            float ls = 0.f, ld_ = 0.f;
#pragma unroll
            for (int ct = 0; ct < 4; ++ct) {
                ls  = fmaf(acc[rt][ct][r], asv[ct], ls);
                ld_ = fmaf(acc[rt][ct][r], adv[ct], ld_);
            }
            for (int off = 8; off; off >>= 1) {
                ls  += __shfl_xor(ls, off);
                ld_ += __shfl_xor(ld_, off);
            }
            if (lr == 0) {
                int lrow = rt * 16 + q * 4 + r;
                als_lds[lrow * 4 + w] = ls;
                ald_lds[lrow * 4 + w] = ld_;
            }
        }
    }
    __syncthreads();

    // ---- pack: pk[row] = {als bf16x4, rscale, 0}; ald4[row] f32x4 ----
    if (tid < 64) {
        int row = row0 + tid;
        if (row < M) {
            float m = fmaxf(fmaxf(rmax_lds[tid * 4 + 0], rmax_lds[tid * 4 + 1]),
                            fmaxf(rmax_lds[tid * 4 + 2], rmax_lds[tid * 4 + 3]));
            uint a01 = (uint)f2b(als_lds[tid * 4 + 0]) | ((uint)f2b(als_lds[tid * 4 + 1]) << 16);
            uint a23 = (uint)f2b(als_lds[tid * 4 + 2]) | ((uint)f2b(als_lds[tid * 4 + 3]) << 16);
            pk[row] = uint4{ a01, a23, __float_as_uint(m * (1.f / 127.f)), 0u };
            ald4[row] = float4{ ald_lds[tid * 4 + 0], ald_lds[tid * 4 + 1],
                                ald_lds[tid * 4 + 2], ald_lds[tid * 4 + 3] };
        }
    }
}

// ---------------- CSR scans ----------------
__global__ __launch_bounds__(256) void scan1(const int* __restrict__ deg, int* __restrict__ out,
                                             int* __restrict__ csum, int N) {
    __shared__ int s[256];
    int t = threadIdx.x;
    int idx0 = blockIdx.x * 1024 + t * 4;
    int v[4];
#pragma unroll
    for (int i = 0; i < 4; ++i) { int id = idx0 + i; v[i] = (id < N) ? deg[id] : 0; }
    int sum = v[0] + v[1] + v[2] + v[3];
    s[t] = sum; __syncthreads();
    for (int off = 1; off < 256; off <<= 1) {
        int x = (t >= off) ? s[t - off] : 0;
        __syncthreads();
        s[t] += x;
        __syncthreads();
    }
    int run = (t == 0) ? 0 : s[t - 1];
#pragma unroll
    for (int i = 0; i < 4; ++i) {
        run += v[i];
        int id = idx0 + i;
        if (id < N) out[id] = run;
    }
    if (t == 255) csum[blockIdx.x] = s[255];
}

__global__ __launch_bounds__(256) void scan3(const int* __restrict__ deg, int* __restrict__ rend,
                                             const int* __restrict__ csum, int* __restrict__ wcur, int N) {
    int id = blockIdx.x * 256 + threadIdx.x;
    if (id >= N) return;
    int chunk = id >> 10;
    int off = 0;
    for (int i = 0; i < chunk; ++i) off += csum[i];
    int e = rend[id] + off;
    rend[id] = e;
    wcur[id] = e - deg[id];
}

// ======== fused softmax (max-free, packed logits) + int8 gather + LN(+res)+ELU ========
template<bool RES, bool FEAT2>
__global__ __launch_bounds__(128) void aggregate_fused(const int* __restrict__ csr_src,
                                                       const int* __restrict__ rend,
                                                       const int* __restrict__ deg_,
                                                       const unsigned char* __restrict__ feat,
                                                       const uint4* __restrict__ pk,
                                                       const float4* __restrict__ ald4,
                                                       const float* __restrict__ bias,
                                                       const float* __restrict__ g,
                                                       const float* __restrict__ bln,
                                                       const ushort* __restrict__ res,
                                                       ushort* __restrict__ out_bf,
                                                       const float* __restrict__ W2,
                                                       const float* __restrict__ as2,
                                                       const float* __restrict__ ad2,
                                                       float4* __restrict__ nf2,
                                                       int N) {
    __shared__ __align__(16) float alds[2][64][4];
    __shared__ int srcs[2][64];
    const int w = threadIdx.x >> 6, l = threadIdx.x & 63;
    const int n = blockIdx.x * 2 + w;
    if (n >= N) return;
    const int dg = deg_[n], end = rend[n], start = end - dg;
    const int hf = l >> 5;
    const int lh = l & 31;
    const int hh = lh >> 3;
    const float4 ad4 = ald4[n];

    float acc[8] = {0.f, 0.f, 0.f, 0.f, 0.f, 0.f, 0.f, 0.f};
    float accC = 0.f;

    auto fma8 = [&](uint2 u, float b) {
        acc[0] = fmaf((float)( u.x        & 0xffu), b, acc[0]);
        acc[1] = fmaf((float)((u.x >>  8) & 0xffu), b, acc[1]);
        acc[2] = fmaf((float)((u.x >> 16) & 0xffu), b, acc[2]);
        acc[3] = fmaf((float)( u.x >> 24         ), b, acc[3]);
        acc[4] = fmaf((float)( u.y        & 0xffu), b, acc[4]);
        acc[5] = fmaf((float)((u.y >>  8) & 0xffu), b, acc[5]);
        acc[6] = fmaf((float)((u.y >> 16) & 0xffu), b, acc[6]);
        acc[7] = fmaf((float)( u.y >> 24         ), b, acc[7]);
        accC += b;
    };

    auto LD = [&](int j) -> uint2 {
        int s = srcs[w][j];
        return *(const uint2*)&feat[(size_t)s * 256 + lh * 8];
    };

    auto gather_chunk = [&](int cnt) {
        int j = hf;
        for (; j + 2 < cnt; j += 4) {
            uint2 u0 = LD(j);
            uint2 u1 = LD(j + 2);
            fma8(u0, alds[w][j][hh]);
            fma8(u1, alds[w][j + 2][hh]);
        }
        for (; j < cnt; j += 2) {
            uint2 u0 = LD(j);
            fma8(u0, alds[w][j][hh]);
        }
    };

    auto exp4_of = [&](uint4 p) -> float4 {
        float4 e;
        e.x = fexp(lrelu(b2f((ushort)(p.x & 0xffff)) + ad4.x));
        e.y = fexp(lrelu(b2f((ushort)(p.x >> 16))    + ad4.y));
        e.z = fexp(lrelu(b2f((ushort)(p.y & 0xffff)) + ad4.z));
        e.w = fexp(lrelu(b2f((ushort)(p.y >> 16))    + ad4.w));
        return e;
    };

    if (dg <= 64) {
        int s = 0;
        float sc = 0.f;
        float4 ex = { 0.f, 0.f, 0.f, 0.f };
        if (l < dg) {
            s = csr_src[start + l];
            uint4 p = pk[s];
            sc = __uint_as_float(p.z);
            ex = exp4_of(p);
        }
        float4 sum = ex;
        for (int off = 32; off; off >>= 1) {
            sum.x += __shfl_xor(sum.x, off);
            sum.y += __shfl_xor(sum.y, off);
            sum.z += __shfl_xor(sum.z, off);
            sum.w += __shfl_xor(sum.w, off);
        }
        float4 al = { ex.x * frcp(sum.x + 1e-16f) * sc, ex.y * frcp(sum.y + 1e-16f) * sc,
                      ex.z * frcp(sum.z + 1e-16f) * sc, ex.w * frcp(sum.w + 1e-16f) * sc };
        *(float4*)&alds[w][l][0] = al;
        srcs[w][l] = s;
        __builtin_amdgcn_s_waitcnt(0);
        gather_chunk(dg);
    } else {
        float4 sum = { 0.f, 0.f, 0.f, 0.f };
        for (int i = l; i < dg; i += 64) {
            int s = csr_src[start + i];
            float4 e = exp4_of(pk[s]);
            sum.x += e.x; sum.y += e.y; sum.z += e.z; sum.w += e.w;
        }
        for (int off = 32; off; off >>= 1) {
            sum.x += __shfl_xor(sum.x, off);
            sum.y += __shfl_xor(sum.y, off);
            sum.z += __shfl_xor(sum.z, off);
            sum.w += __shfl_xor(sum.w, off);
        }
        float4 inv = { frcp(sum.x + 1e-16f), frcp(sum.y + 1e-16f),
                       frcp(sum.z + 1e-16f), frcp(sum.w + 1e-16f) };
        for (int c0 = start; c0 < end; c0 += 64) {
            int cnt = min(64, end - c0);
            if (l < cnt) {
                int s = csr_src[c0 + l];
                uint4 p = pk[s];
                float sc = __uint_as_float(p.z);
                float4 e = exp4_of(p);
                float4 al = { e.x * inv.x * sc, e.y * inv.y * sc,
                              e.z * inv.z * sc, e.w * inv.w * sc };
                *(float4*)&alds[w][l][0] = al;
                srcs[w][l] = s;
            }
            __builtin_amdgcn_s_waitcnt(0);
            gather_chunk(cnt);
        }
    }

#pragma unroll
    for (int r = 0; r < 8; ++r) acc[r] += __shfl_xor(acc[r], 32);
    accC += __shfl_xor(accC, 32);

    float4 bv0 = ((const float4*)bias)[lh * 2];
    float4 bv1 = ((const float4*)bias)[lh * 2 + 1];
    float c128 = 128.f * accC;
    float v[8] = { acc[0] - c128 + bv0.x, acc[1] - c128 + bv0.y,
                   acc[2] - c128 + bv0.z, acc[3] - c128 + bv0.w,
                   acc[4] - c128 + bv1.x, acc[5] - c128 + bv1.y,
                   acc[6] - c128 + bv1.z, acc[7] - c128 + bv1.w };
    float sm = v[0] + v[1] + v[2] + v[3] + v[4] + v[5] + v[6] + v[7];
    for (int off = 32; off; off >>= 1) sm += __shfl_xor(sm, off);
    float mu = sm * (1.f / (2 * F1));
    float dv = 0.f;
#pragma unroll
    for (int r = 0; r < 8; ++r) { float d = v[r] - mu; dv += d * d; }
    for (int off = 32; off; off >>= 1) dv += __shfl_xor(dv, off);
    float rstd = rsqrtf(dv * (1.f / (2 * F1)) + LN_EPS);
    float4 gv0 = ((const float4*)g)[lh * 2],   gv1 = ((const float4*)g)[lh * 2 + 1];
    float4 lb0 = ((const float4*)bln)[lh * 2], lb1 = ((const float4*)bln)[lh * 2 + 1];
    float y[8];
    y[0] = (v[0] - mu) * rstd * gv0.x + lb0.x;
    y[1] = (v[1] - mu) * rstd * gv0.y + lb0.y;
    y[2] = (v[2] - mu) * rstd * gv0.z + lb0.z;
    y[3] = (v[3] - mu) * rstd * gv0.w + lb0.w;
    y[4] = (v[4] - mu) * rstd * gv1.x + lb1.x;
    y[5] = (v[5] - mu) * rstd * gv1.y + lb1.y;
    y[6] = (v[6] - mu) * rstd * gv1.z + lb1.z;
    y[7] = (v[7] - mu) * rstd * gv1.w + lb1.w;
    if (RES) {
        uint4 rr = ((const uint4*)res)[(size_t)n * 32 + lh];
        y[0] += __uint_as_float(rr.x << 16);
        y[1] += __uint_as_float(rr.x & 0xffff0000u);
        y[2] += __uint_as_float(rr.y << 16);
        y[3] += __uint_as_float(rr.y & 0xffff0000u);
        y[4] += __uint_as_float(rr.z << 16);
        y[5] += __uint_as_float(rr.z & 0xffff0000u);
        y[6] += __uint_as_float(rr.w << 16);
        y[7] += __uint_as_float(rr.w & 0xffff0000u);
    }
#pragma unroll
    for (int r = 0; r < 8; ++r) y[r] = y[r] > 0.f ? y[r] : fexp(y[r]) - 1.f;

    if (!FEAT2) {
        if (l < 32) {
            uint4 o;
            o.x = (uint)f2b(y[0]) | ((uint)f2b(y[1]) << 16);
            o.y = (uint)f2b(y[2]) | ((uint)f2b(y[3]) << 16);
            o.z = (uint)f2b(y[4]) | ((uint)f2b(y[5]) << 16);
            o.w = (uint)f2b(y[6]) | ((uint)f2b(y[7]) << 16);
            ((uint4*)out_bf)[(size_t)n * 32 + lh] = o;
        }
    } else {
        const float4* W24 = (const float4*)W2;
        float c0 = 0.f, c1 = 0.f;
#pragma unroll
        for (int j = 0; j < 4; ++j) {
            float4 wv = W24[lh * 4 + j];
            c0 += y[2 * j] * wv.x + y[2 * j + 1] * wv.z;
            c1 += y[2 * j] * wv.y + y[2 * j + 1] * wv.w;
        }
        for (int off = 32; off; off >>= 1) {
            c0 += __shfl_xor(c0, off);
            c1 += __shfl_xor(c1, off);
        }
        c0 *= 0.5f; c1 *= 0.5f;
        if (l == 0) {
            float4 o = { c0, c1,
                         c0 * as2[0] + c1 * as2[1],
                         c0 * ad2[0] + c1 * ad2[1] };
            nf2[n] = o;
        }
    }
}

// ---- layer 2 fully fused (max-free softmax) ----
__global__ __launch_bounds__(128) void layer2_fused(const int* __restrict__ csr_src,
                                                    const int* __restrict__ rend,
                                                    const int* __restrict__ deg_,
                                                    const float4* __restrict__ nf2,
                                                    const float* __restrict__ b2,
                                                    float* __restrict__ out, int N) {
    const int w = threadIdx.x >> 6, l = threadIdx.x & 63;
    const int n = blockIdx.x * 2 + w;
    if (n >= N) return;
    const int dg = deg_[n], end = rend[n], start = end - dg;
    const float ad = nf2[n].w;

    float a0 = 0.f, a1 = 0.f;
    if (dg <= 64) {
        float ex = 0.f;
        float f0 = 0.f, f1 = 0.f;
        if (l < dg) {
            int s = csr_src[start + l];
            float4 v = nf2[s];
            ex = fexp(lrelu(v.z + ad));
            f0 = v.x; f1 = v.y;
        }
        float sum = ex;
        for (int off = 32; off; off >>= 1) sum += __shfl_xor(sum, off);
        float al = ex * frcp(sum + 1e-16f);
        a0 = f0 * al; a1 = f1 * al;
    } else {
        float sum = 0.f;
        for (int i = l; i < dg; i += 64) {
            int s = csr_src[start + i];
            sum += fexp(lrelu(nf2[s].z + ad));
        }
        for (int off = 32; off; off >>= 1) sum += __shfl_xor(sum, off);
        float inv = frcp(sum + 1e-16f);
        for (int i = l; i < dg; i += 64) {
            int s = csr_src[start + i];
            float4 v = nf2[s];
            float al = fexp(lrelu(v.z + ad)) * inv;
            a0 = fmaf(v.x, al, a0);
            a1 = fmaf(v.y, al, a1);
        }
    }
    for (int off = 32; off; off >>= 1) {
        a0 += __shfl_xor(a0, off);
        a1 += __shfl_xor(a1, off);
    }
    if (l == 0) {
        out[(size_t)n * 2 + 0] = a0 + b2[0];
        out[(size_t)n * 2 + 1] = a1 + b2[1];
    }
}

extern "C" void kernel_launch(void* const* d_in, const int* in_sizes, int n_in,
                              void* d_out, int out_size, void* d_ws, size_t ws_size,
                              hipStream_t stream) {
    const float* x    = (const float*)d_in[0];
    const int*   ei   = (const int*)d_in[1];
    const float* Wp   = (const float*)d_in[2];
    const float* bp   = (const float*)d_in[3];
    const float* W0   = (const float*)d_in[4];
    const float* as0  = (const float*)d_in[5];
    const float* ad0  = (const float*)d_in[6];
    const float* b0   = (const float*)d_in[7];
    const float* W1   = (const float*)d_in[8];
    const float* as1  = (const float*)d_in[9];
    const float* ad1  = (const float*)d_in[10];
    const float* b1   = (const float*)d_in[11];
    const float* W2   = (const float*)d_in[12];
    const float* as2  = (const float*)d_in[13];
    const float* ad2  = (const float*)d_in[14];
    const float* b2   = (const float*)d_in[15];
    const float* ln_g = (const float*)d_in[16];
    const float* ln_b = (const float*)d_in[17];
    float* out = (float*)d_out;

    const int N    = in_sizes[0] / IN_DIM;   // 50000
    const int E    = in_sizes[1] / 2;        // 800000
    const int Etot = E + N;

    char* wptr = (char*)d_ws;
    auto alloc = [&](size_t bytes) -> void* {
        void* p = wptr;
        wptr += (bytes + 255) & ~(size_t)255;
        return p;
    };
    unsigned char* F8 = (unsigned char*)alloc((size_t)N * F1);
    uint4*  pk     = (uint4*)alloc(sizeof(uint4) * (size_t)N);
    float4* ald4   = (float4*)alloc(sizeof(float4) * (size_t)N);
    ushort* Ab     = (ushort*)alloc(sizeof(ushort) * (size_t)N * F1);
    float4* nf2    = (float4*)alloc(sizeof(float4) * (size_t)N);
    ushort* Wf0    = (ushort*)alloc(sizeof(ushort) * (size_t)F1 * KP);
    float*  bc     = (float*)alloc(sizeof(float) * F1);
    ushort* Wf1    = (ushort*)alloc(sizeof(ushort) * (size_t)F1 * F1);
    int*    deg    = (int*)alloc(sizeof(int) * (size_t)N);
    int*    rend   = (int*)alloc(sizeof(int) * (size_t)N);
    int*    wcur   = (int*)alloc(sizeof(int) * (size_t)N);
    int*    csum   = (int*)alloc(sizeof(int) * 256);
    int*    csrs   = (int*)alloc(sizeof(int) * (size_t)Etot);

    const int eb   = (Etot + 255) / 256;
    const int eb2  = (Etot + 511) / 512;     // fill blocks (2 edges/thread)
    const int nb   = (N + 255) / 256;
    const int nb2  = (N + 1) / 2;
    const int nchunks = (N + 1023) / 1024;
    const int mb64 = (N + 63) / 64;

    // -------- weight prep + csr degree count (one dispatch) --------
    hipMemsetAsync(deg, 0, sizeof(int) * (size_t)N, stream);
    weight_prep<<<KP + F1 + eb, 256, 0, stream>>>(Wp, W0, bp, W1, Wf0, bc, Wf1,
                                                  ei, E, Etot, deg);

    // -------- CSR scans --------
    scan1<<<nchunks, 256, 0, stream>>>(deg, rend, csum, N);
    scan3<<<nb, 256, 0, stream>>>(deg, rend, csum, wcur, N);

    // ====== layer 0 GEMM + csr_fill, role-interleaved (every 3rd block = GEMM) ======
    mfma_gemm2<KP / 32, true><<<mb64 + eb2, 256, 0, stream>>>(
        x, Wf0, bc, as0, ad0, F8, pk, ald4, N,
        mb64, ei, E, Etot, wcur, csrs);
    aggregate_fused<false, false><<<nb2, 128, 0, stream>>>(csrs, rend, deg, F8, pk, ald4,
        b0, ln_g, ln_b, nullptr, Ab, nullptr, nullptr, nullptr, nullptr, N);

    // ================= layer 1 =================
    mfma_gemm2<F1 / 32, false><<<mb64, 256, 0, stream>>>(
        Ab, Wf1, nullptr, as1, ad1, F8, pk, ald4, N,
        mb64, nullptr, 0, 0, nullptr, nullptr);
    aggregate_fused<true, true><<<nb2, 128, 0, stream>>>(csrs, rend, deg, F8, pk, ald4,
        b1, ln_g, ln_b, Ab, nullptr, W2, as2, ad2, nf2, N);

    // ================= layer 2 =================
    layer2_fused<<<nb2, 128, 0, stream>>>(csrs, rend, deg, nf2, b2, out, N);
}